// Round 11
// baseline (119.411 us; speedup 1.0000x reference)
//
#include <hip/hip_runtime.h>
#include <stdint.h>

// IDXST(4096x4096): y[r][k] = sum_n x[r][n] sin(pi*n*(2k+1)/8192.
// R16: R15's quad-closed grid (combine fused into epilogue) with HALF-SIZE
// BLOCKS for 2-blocks/CU TLP. R15 accounting: MFMA floor 24.8us + LDS-read
// window 36us SERIALIZED by single-block barrier lockstep = 61 ~= 65.6us
// measured. Cross-block TLP (m114) overlaps the two windows; R12's attempt
// failed residency at 2x80KB=160KB exactly. Now: 512 blocks x 256 threads
// (4 waves, 2Mx2N), each 128 rows x one quad col-group; LDS 48KB (A dbuf
// 32K + B 16K; P,Q segments run SEQUENTIALLY reusing regions) -> 96KB/CU,
// residency guaranteed. All 512 blocks identical (100.5 MF): balance-free.
// Same proven 4-phase skeleton + strip-gather + register fold epilogue.
//   U seg:  128x128, K=2048, B_U = [S1 fwd|S4 rev|S2 rev|S3 fwd] (16KB).
//   P seg:  128x64, K=1024, B_P = [S1' fwd|S2' rev] (8KB); then Q likewise.
// Epilogue: y = u +- (p +- q) written once (R15-verified mapping, wm in 0..1).
// ws (44 MB): xo 16 | xee 8 | xeo 8 | Bo 8 | Bp 2 | Bq 2. prep unchanged.

#define NN 4096

typedef __attribute__((ext_vector_type(8))) short short8;
typedef __attribute__((ext_vector_type(4))) float f32x4;

__device__ __forceinline__ unsigned short f2bf(float f) {
  unsigned int u = __float_as_uint(f);
  u += 0x7fffu + ((u >> 16) & 1u);
  return (unsigned short)(u >> 16);
}

__device__ __forceinline__ void async_load16(const void* g, void* lds) {
  __builtin_amdgcn_global_load_lds(
      (const __attribute__((address_space(1))) unsigned int*)g,
      (__attribute__((address_space(3))) unsigned int*)lds, 16, 0, 0);
}

#define NXS (NN * NN / 8)        // 2M x-split threads (8 floats each)
#define NBO (2048 * 2048 / 4)    // 1M Bo threads
#define NBP (1024 * 1024 / 4)    // 256K Bp threads (Bq same)

// prep: xo[r][m]=x[r][2m+1]; xee[r][t]=x[r][4t]; xeo[r][t]=x[r][4t+2];
// Bo[c][m]=sin(pi(2m+1)(2c+1)/8192); Bp[c][t]=sin(pi*t*(2c+1)/2048);
// Bq[c][t]=sin(pi(2t+1)(2c+1)/4096)
__global__ void prep_kernel(const float* __restrict__ x,
                            unsigned short* __restrict__ xo,
                            unsigned short* __restrict__ xee,
                            unsigned short* __restrict__ xeo,
                            unsigned short* __restrict__ Bo,
                            unsigned short* __restrict__ Bp,
                            unsigned short* __restrict__ Bq) {
  int gi = blockIdx.x * blockDim.x + threadIdx.x;
  if (gi < NXS) {
    int g = gi & 511;            // 8-float group in row
    int r = gi >> 9;
    const float4* src = (const float4*)(x + (size_t)r * NN + g * 8);
    float4 v0 = src[0], v1 = src[1];    // n = 8g+0..3, 8g+4..7
    ushort4 ov;                          // odd n -> m = 4g..4g+3
    ov.x = f2bf(v0.y); ov.y = f2bf(v0.w); ov.z = f2bf(v1.y); ov.w = f2bf(v1.w);
    *(ushort4*)&xo[(size_t)r * 2048 + g * 4] = ov;
    unsigned int ee = ((unsigned)f2bf(v1.x) << 16) | f2bf(v0.x);  // t=2g,2g+1
    *(unsigned int*)&xee[(size_t)r * 1024 + g * 2] = ee;
    unsigned int eo = ((unsigned)f2bf(v1.z) << 16) | f2bf(v0.z);
    *(unsigned int*)&xeo[(size_t)r * 1024 + g * 2] = eo;
  } else if (gi < NXS + NBO) {
    int i = gi - NXS;
    int m0 = (i & 511) * 4;
    int c = i >> 9;
    unsigned int tw = 2u * (unsigned)c + 1u;
    const float sc = 3.14159265358979323846f / 8192.0f;
    ushort4 o; unsigned int ph;
    ph = ((unsigned)(2 * (m0 + 0) + 1) * tw) & 16383u; o.x = f2bf(__sinf((float)ph * sc));
    ph = ((unsigned)(2 * (m0 + 1) + 1) * tw) & 16383u; o.y = f2bf(__sinf((float)ph * sc));
    ph = ((unsigned)(2 * (m0 + 2) + 1) * tw) & 16383u; o.z = f2bf(__sinf((float)ph * sc));
    ph = ((unsigned)(2 * (m0 + 3) + 1) * tw) & 16383u; o.w = f2bf(__sinf((float)ph * sc));
    *(ushort4*)&Bo[(size_t)c * 2048 + m0] = o;
  } else if (gi < NXS + NBO + NBP) {
    int i = gi - NXS - NBO;
    int t0 = (i & 255) * 4;
    int c = i >> 8;
    unsigned int tw = 2u * (unsigned)c + 1u;
    const float sc = 3.14159265358979323846f / 2048.0f;
    ushort4 o; unsigned int ph;
    ph = ((unsigned)(t0 + 0) * tw) & 4095u; o.x = f2bf(__sinf((float)ph * sc));
    ph = ((unsigned)(t0 + 1) * tw) & 4095u; o.y = f2bf(__sinf((float)ph * sc));
    ph = ((unsigned)(t0 + 2) * tw) & 4095u; o.z = f2bf(__sinf((float)ph * sc));
    ph = ((unsigned)(t0 + 3) * tw) & 4095u; o.w = f2bf(__sinf((float)ph * sc));
    *(ushort4*)&Bp[(size_t)c * 1024 + t0] = o;
  } else {
    int i = gi - NXS - NBO - NBP;
    int t0 = (i & 255) * 4;
    int c = i >> 8;
    unsigned int tw = 2u * (unsigned)c + 1u;
    const float sc = 3.14159265358979323846f / 4096.0f;
    ushort4 o; unsigned int ph;
    ph = ((unsigned)(2 * (t0 + 0) + 1) * tw) & 8191u; o.x = f2bf(__sinf((float)ph * sc));
    ph = ((unsigned)(2 * (t0 + 1) + 1) * tw) & 8191u; o.y = f2bf(__sinf((float)ph * sc));
    ph = ((unsigned)(2 * (t0 + 2) + 1) * tw) & 8191u; o.z = f2bf(__sinf((float)ph * sc));
    ph = ((unsigned)(2 * (t0 + 3) + 1) * tw) & 8191u; o.w = f2bf(__sinf((float)ph * sc));
    *(ushort4*)&Bq[(size_t)c * 1024 + t0] = o;
  }
}

// ---- LDS layout (ushort indices), 48 KiB total --------------------------
// A buf0 [0,8192) | A buf1 [8192,16384) | B [16384,24576)
// (B_U uses the full 16 KB = 128 cols; B_P/B_Q use [16384,20480) = 64 cols)
#define PH_BAR  __builtin_amdgcn_s_barrier()
#define W_LGKM0 asm volatile("s_waitcnt lgkmcnt(0)" ::: "memory")
#define W_VM0   asm volatile("s_waitcnt vmcnt(0)" ::: "memory")
#define PRIO1   __builtin_amdgcn_s_setprio(1)
#define PRIO0   __builtin_amdgcn_s_setprio(0)

// Stage 64 A rows (prow0+st_r, prow0+32+st_r) x 64 k = 8KB, 2 loads/thread.
// Linear LDS dest; source chunk pre-swizzled by chunk^(row&7).
#define STAGEA_H(Abase, Kc, prow0, koff, off) do {                              \
    const unsigned short* _s =                                                  \
        (Abase) + (size_t)((prow0) + st_r) * (Kc) + (koff) + st_c;              \
    async_load16(_s, &lds[(off) + tid * 8]);                                    \
    async_load16(_s + (size_t)32 * (Kc), &lds[(off) + 2048 + tid * 8]);         \
  } while (0)

// Stage one 32-row B chunk (4KB, 1 load/thread) from a per-thread strip ptr.
#define STAGEB_P(srcp, koff, off)                                               \
    async_load16((srcp) + (koff), &lds[(off) + tid * 8])

// A-frags for row-half mh (32 rows) of buffer b: 4 ds_read_b128.
// row = wm*64 + mh*32 + i*16 + lr.
#define LOADA(b, mh) do {                                                       \
    const int _ab = (b) * 8192 + wm * 4096 + (mh) * 2048 + lr * 64;             \
    _Pragma("unroll") for (int _i = 0; _i < 2; ++_i) {                          \
      av[(mh) * 2 + _i][0] = *(const short8*)&lds[_ab + _i * 1024 + cA0];       \
      av[(mh) * 2 + _i][1] = *(const short8*)&lds[_ab + _i * 1024 + cA1];       \
    }                                                                           \
  } while (0)

// U B-frags for col-half nh: cols wn*64 + nh*32 + j*16 + lr. 4 b128.
#define LOADB_U(SET, nh) do {                                                   \
    const int _bb = 16384 + wn * 4096 + (nh) * 2048 + lr * 64;                  \
    _Pragma("unroll") for (int _j = 0; _j < 2; ++_j) {                          \
      SET[_j][0] = *(const short8*)&lds[_bb + _j * 1024 + cA0];                 \
      SET[_j][1] = *(const short8*)&lds[_bb + _j * 1024 + cA1];                 \
    }                                                                           \
  } while (0)

// PQ B-frags: cols wn*32 + j*16 + lr of the 64-col B region. 4 b128.
#define LOADB_PQ(SET) do {                                                      \
    const int _bb = 16384 + wn * 2048 + lr * 64;                                \
    _Pragma("unroll") for (int _j = 0; _j < 2; ++_j) {                          \
      SET[_j][0] = *(const short8*)&lds[_bb + _j * 1024 + cA0];                 \
      SET[_j][1] = *(const short8*)&lds[_bb + _j * 1024 + cA1];                 \
    }                                                                           \
  } while (0)

// U quadrant (32x32) x K=64: 8 MFMA into uacc.
#define MMAQ_U(BS, mh, nh) do {                                                 \
    _Pragma("unroll") for (int _k = 0; _k < 2; ++_k)                            \
    _Pragma("unroll") for (int _i = 0; _i < 2; ++_i)                            \
    _Pragma("unroll") for (int _j = 0; _j < 2; ++_j)                            \
      uacc[(mh) * 2 + _i][(nh) * 2 + _j] =                                      \
          __builtin_amdgcn_mfma_f32_16x16x32_bf16(                              \
              av[(mh) * 2 + _i][_k], BS[_j][_k],                                \
              uacc[(mh) * 2 + _i][(nh) * 2 + _j], 0, 0, 0);                     \
  } while (0)

// P/Q row-half (32 rows x 32 cols) x K=64: 8 MFMA into ACC.
#define MMAQ_PQ(ACC, BS, mh) do {                                               \
    _Pragma("unroll") for (int _k = 0; _k < 2; ++_k)                            \
    _Pragma("unroll") for (int _i = 0; _i < 2; ++_i)                            \
    _Pragma("unroll") for (int _j = 0; _j < 2; ++_j)                            \
      ACC[(mh) * 2 + _i][_j] =                                                  \
          __builtin_amdgcn_mfma_f32_16x16x32_bf16(                              \
              av[(mh) * 2 + _i][_k], BS[_j][_k],                                \
              ACC[(mh) * 2 + _i][_j], 0, 0, 0);                                 \
  } while (0)

__global__ __launch_bounds__(256) void gemm3_kernel(
    const unsigned short* __restrict__ xo,
    const unsigned short* __restrict__ xee,
    const unsigned short* __restrict__ xeo,
    const unsigned short* __restrict__ Bo,
    const unsigned short* __restrict__ Bp,
    const unsigned short* __restrict__ Bq,
    float* __restrict__ out) {
  __shared__ __align__(16) unsigned short lds[24576];   // 48 KiB -> 2 blk/CU

  const int bx = blockIdx.x;           // 512 identical blocks
  const int row0 = (bx & 31) * 128;
  const int c0 = (bx >> 5) * 32;       // quad-group base k'

  const int tid = threadIdx.x;
  const int lane = tid & 63;
  const int wave = tid >> 6;
  const int wm = wave >> 1;            // 0..1 : 64-row strip
  const int wn = wave & 1;             // 0..1 : col-half (strip pair)
  const int lr = lane & 15, kq = lane >> 4;
  const int st_r = tid >> 3;                         // staging row 0..31
  const int st_c = ((tid & 7) ^ (st_r & 7)) * 8;     // pre-swizzled src chunk
  const int cA0 = (kq ^ (lr & 7)) * 8;               // swizzled ds_read chunks
  const int cA1 = ((4 + kq) ^ (lr & 7)) * 8;

  // Per-thread B staging strip pointers (mirror strips in reversed order).
  const unsigned short* sU1 = Bo + (size_t)(c0 + st_r) * 2048 + st_c;
  const unsigned short* sU4 = Bo + (size_t)(2047 - c0 - st_r) * 2048 + st_c;
  const unsigned short* sU2 = Bo + (size_t)(1023 - c0 - st_r) * 2048 + st_c;
  const unsigned short* sU3 = Bo + (size_t)(1024 + c0 + st_r) * 2048 + st_c;
  const unsigned short* sP1 = Bp + (size_t)(c0 + st_r) * 1024 + st_c;
  const unsigned short* sP2 = Bp + (size_t)(1023 - c0 - st_r) * 1024 + st_c;
  const unsigned short* sQ1 = Bq + (size_t)(c0 + st_r) * 1024 + st_c;
  const unsigned short* sQ2 = Bq + (size_t)(1023 - c0 - st_r) * 1024 + st_c;

  f32x4 uacc[4][4], pacc[4][2], qacc[4][2];
#pragma unroll
  for (int i = 0; i < 4; ++i) {
#pragma unroll
    for (int j = 0; j < 4; ++j) uacc[i][j] = (f32x4){0.f, 0.f, 0.f, 0.f};
#pragma unroll
    for (int j = 0; j < 2; ++j) {
      pacc[i][j] = (f32x4){0.f, 0.f, 0.f, 0.f};
      qacc[i][j] = (f32x4){0.f, 0.f, 0.f, 0.f};
    }
  }
  short8 av[4][2], bv0[2][2], bv1[2][2];

  // ================= U segment: 128x128, K=2048, 32 K-tiles ================
  STAGEA_H(xo, 2048, row0,      0, 0);
  STAGEA_H(xo, 2048, row0 + 64, 0, 4096);
  STAGEB_P(sU1, 0, 16384);
  STAGEB_P(sU4, 0, 18432);
  STAGEB_P(sU2, 0, 20480);
  STAGEB_P(sU3, 0, 22528);
  W_VM0; PH_BAR;

  for (int it = 0; it < 15; ++it) {
    const int t64 = it << 7;
    // tile t (buf0), stage tile t+1 -> buf1
    LOADA(0, 0); LOADB_U(bv0, 0);
    STAGEA_H(xo, 2048, row0, t64 + 64, 8192);
    PH_BAR; W_LGKM0; PRIO1; MMAQ_U(bv0, 0, 0); PRIO0; PH_BAR;
    LOADB_U(bv1, 1);
    STAGEA_H(xo, 2048, row0 + 64, t64 + 64, 12288);
    PH_BAR; W_LGKM0; PRIO1; MMAQ_U(bv1, 0, 1); PRIO0; PH_BAR;
    LOADA(0, 1);
    STAGEB_P(sU1, t64 + 64, 16384);
    STAGEB_P(sU4, t64 + 64, 18432);
    STAGEB_P(sU2, t64 + 64, 20480);
    STAGEB_P(sU3, t64 + 64, 22528);
    PH_BAR; W_LGKM0; PRIO1; MMAQ_U(bv1, 1, 1); PRIO0; PH_BAR;
    PRIO1; MMAQ_U(bv0, 1, 0); PRIO0; W_VM0; PH_BAR;
    // tile t+1 (buf1), stage tile t+2 -> buf0
    LOADA(1, 0); LOADB_U(bv0, 0);
    STAGEA_H(xo, 2048, row0, t64 + 128, 0);
    PH_BAR; W_LGKM0; PRIO1; MMAQ_U(bv0, 0, 0); PRIO0; PH_BAR;
    LOADB_U(bv1, 1);
    STAGEA_H(xo, 2048, row0 + 64, t64 + 128, 4096);
    PH_BAR; W_LGKM0; PRIO1; MMAQ_U(bv1, 0, 1); PRIO0; PH_BAR;
    LOADA(1, 1);
    STAGEB_P(sU1, t64 + 128, 16384);
    STAGEB_P(sU4, t64 + 128, 18432);
    STAGEB_P(sU2, t64 + 128, 20480);
    STAGEB_P(sU3, t64 + 128, 22528);
    PH_BAR; W_LGKM0; PRIO1; MMAQ_U(bv1, 1, 1); PRIO0; PH_BAR;
    PRIO1; MMAQ_U(bv0, 1, 0); PRIO0; W_VM0; PH_BAR;
  }
  { // peel: tile 30 (buf0) stages tile 31 -> buf1; tile 31 barrier-free
    LOADA(0, 0); LOADB_U(bv0, 0);
    STAGEA_H(xo, 2048, row0, 1984, 8192);
    PH_BAR; W_LGKM0; PRIO1; MMAQ_U(bv0, 0, 0); PRIO0; PH_BAR;
    LOADB_U(bv1, 1);
    STAGEA_H(xo, 2048, row0 + 64, 1984, 12288);
    PH_BAR; W_LGKM0; PRIO1; MMAQ_U(bv1, 0, 1); PRIO0; PH_BAR;
    LOADA(0, 1);
    STAGEB_P(sU1, 1984, 16384);
    STAGEB_P(sU4, 1984, 18432);
    STAGEB_P(sU2, 1984, 20480);
    STAGEB_P(sU3, 1984, 22528);
    PH_BAR; W_LGKM0; PRIO1; MMAQ_U(bv1, 1, 1); PRIO0; PH_BAR;
    PRIO1; MMAQ_U(bv0, 1, 0); PRIO0; W_VM0; PH_BAR;
    LOADA(1, 0); LOADB_U(bv0, 0);
    W_LGKM0; PRIO1; MMAQ_U(bv0, 0, 0); PRIO0;
    LOADB_U(bv1, 1);
    W_LGKM0; PRIO1; MMAQ_U(bv1, 0, 1); PRIO0;
    LOADA(1, 1);
    W_LGKM0; PRIO1; MMAQ_U(bv1, 1, 1); MMAQ_U(bv0, 1, 0); PRIO0;
  }

  // One P/Q K-tile in buffer b, staging tile t+1 (k-offset kn) -> buffer b^1.
  // 2 phases: p1 {LOADA h0 + LOADB, stage A[t+1]h0, 8 MFMA},
  //           p2 {LOADA h1, stage A[t+1]h1 + B[t+1], 8 MFMA, vmcnt(0)}.
  // B region last read p1 (sealed by p1 trailing barrier) -> restage in p2.
#define PQ_TILE(ACC, Asrc, s1, s2, b, kn) do {                                  \
    LOADA(b, 0); LOADB_PQ(bv0);                                                 \
    STAGEA_H(Asrc, 1024, row0, kn, ((b) ^ 1) * 8192);                           \
    PH_BAR; W_LGKM0; PRIO1; MMAQ_PQ(ACC, bv0, 0); PRIO0; PH_BAR;                \
    LOADA(b, 1);                                                                \
    STAGEA_H(Asrc, 1024, row0 + 64, kn, ((b) ^ 1) * 8192 + 4096);               \
    STAGEB_P(s1, kn, 16384);                                                    \
    STAGEB_P(s2, kn, 18432);                                                    \
    PH_BAR; W_LGKM0; PRIO1; MMAQ_PQ(ACC, bv0, 1); PRIO0; W_VM0; PH_BAR;         \
  } while (0)

#define PQ_SEG(ACC, Asrc, s1, s2) do {                                          \
    PH_BAR;                                                                     \
    STAGEA_H(Asrc, 1024, row0,      0, 0);                                      \
    STAGEA_H(Asrc, 1024, row0 + 64, 0, 4096);                                   \
    STAGEB_P(s1, 0, 16384);                                                     \
    STAGEB_P(s2, 0, 18432);                                                     \
    W_VM0; PH_BAR;                                                              \
    for (int it = 0; it < 7; ++it) {                                            \
      const int t64 = it << 7;                                                  \
      PQ_TILE(ACC, Asrc, s1, s2, 0, t64 + 64);                                  \
      PQ_TILE(ACC, Asrc, s1, s2, 1, t64 + 128);                                 \
    }                                                                           \
    PQ_TILE(ACC, Asrc, s1, s2, 0, 960);                                         \
    LOADA(1, 0); LOADB_PQ(bv0);                                                 \
    W_LGKM0; PRIO1; MMAQ_PQ(ACC, bv0, 0); PRIO0;                                \
    LOADA(1, 1);                                                                \
    W_LGKM0; PRIO1; MMAQ_PQ(ACC, bv0, 1); PRIO0;                                \
  } while (0)

  // ============== P segment (xee/Bp), then Q segment (xeo/Bq) ==============
  PQ_SEG(pacc, xee, sP1, sP2);
  PQ_SEG(qacc, xeo, sQ1, sQ2);
#undef PQ_TILE
#undef PQ_SEG

  // ===================== epilogue: full two-level fold =====================
  // wn=0: u1=u[k'], u4=u[2047-k'], p/q at k'.  wn=1: u1=u[1023-k'],
  // u4=u[1024+k'], p/q at 1023-k'.  k' = c0+cs, cs = j*16+lr.
#pragma unroll
  for (int i = 0; i < 4; ++i)
#pragma unroll
    for (int j = 0; j < 2; ++j)
#pragma unroll
      for (int rr = 0; rr < 4; ++rr) {
        const int r_out = row0 + wm * 64 + i * 16 + kq * 4 + rr;
        float* orow = out + (size_t)r_out * NN;
        const int cs = j * 16 + lr;
        const float u1 = uacc[i][j][rr];
        const float u4 = uacc[i][j + 2][rr];
        const float pa = pacc[i][j][rr];
        const float qa = qacc[i][j][rr];
        const float v1 = pa + qa;
        const float v2 = qa - pa;
        if (wn == 0) {
          orow[c0 + cs]        = v1 + u1;   // y[k']
          orow[4095 - c0 - cs] = u1 - v1;   // y[4095-k']
          orow[2047 - c0 - cs] = v2 + u4;   // y[2047-k']
          orow[2048 + c0 + cs] = u4 - v2;   // y[2048+k']
        } else {
          orow[1023 - c0 - cs] = v1 + u1;   // y[1023-k']
          orow[3072 + c0 + cs] = u1 - v1;   // y[3072+k']
          orow[1024 + c0 + cs] = v2 + u4;   // y[1024+k']
          orow[3071 - c0 - cs] = u4 - v2;   // y[3071-k']
        }
      }
}

extern "C" void kernel_launch(void* const* d_in, const int* in_sizes, int n_in,
                              void* d_out, int out_size, void* d_ws, size_t ws_size,
                              hipStream_t stream) {
  const float* x = (const float*)d_in[0];
  float* out = (float*)d_out;
  unsigned short* xo  = (unsigned short*)d_ws;            // 16 MB
  unsigned short* xee = xo + (size_t)NN * 2048;           // 8 MB
  unsigned short* xeo = xee + (size_t)NN * 1024;          // 8 MB
  unsigned short* Bo  = xeo + (size_t)NN * 1024;          // 8 MB
  unsigned short* Bp  = Bo + (size_t)2048 * 2048;         // 2 MB
  unsigned short* Bq  = Bp + (size_t)1024 * 1024;         // 2 MB -> 44 MB total

  int prep_threads = NXS + NBO + 2 * NBP;
  prep_kernel<<<prep_threads / 256, 256, 0, stream>>>(x, xo, xee, xeo, Bo, Bp, Bq);

  gemm3_kernel<<<512, 256, 0, stream>>>(xo, xee, xeo, Bo, Bp, Bq, out);
}